// Round 15
// baseline (449.235 us; speedup 1.0000x reference)
//
#include <hip/hip_runtime.h>

#pragma clang fp contract(off)

#define HQ 384
#define WQ 384
#define NC 64
#define HFD 48
#define HID 256
#define NPIX (4 * HQ * WQ)
#define PPB 128  // pixels per block
#define NTHR 512 // 8 waves; hidden layers: wave = 1 j'-tile(32j) x 4 px-tiles(32px)

typedef _Float16 half8 __attribute__((ext_vector_type(8)));
typedef __fp16 fp16x2 __attribute__((ext_vector_type(2)));   // cvt_pkrtz native type
typedef float f32x4 __attribute__((ext_vector_type(4)));
typedef float f32x16 __attribute__((ext_vector_type(16)));
typedef unsigned int u32;
typedef unsigned short u16;

// ws layout in u32 units: per layer, A=W^T fragments, hi then lo(residual).
// Hidden layers use 32x32x16 A-frags: entry = ((T*NS+s)*64+lane)*4+i,
//   j' = T*32+(lane&31), k = s*16+(lane>>5)*8+2i(+1). L0: NT=8,NS=6 ; L1-3: NT=8,NS=16.
// L4 (final 256->3) keeps 16x16x32 frags: NT=1, NS=8.
#define O0H 0
#define O0L 12288
#define O1H 24576
#define O1L 57344
#define O2H 90112
#define O2L 122880
#define O3H 155648
#define O3L 188416
#define O4H 221184
#define O4L 223232
// total 225280 u32 = 901120 bytes of d_ws used

__device__ __forceinline__ u32 pkrtz(float a, float b) {
    fp16x2 h = __builtin_amdgcn_cvt_pkrtz(a, b);   // v_cvt_pkrtz_f16_f32
    return __builtin_bit_cast(u32, h);
}

// ---------------------------------------------------------------------------
// Nearest-sample index per grid_sample(nearest, align_corners=False).
// Exact f32 op sequence (contraction off file-wide). Validated on HW (r3/r5).
// ---------------------------------------------------------------------------
__device__ __forceinline__ int nearest_idx(float g, bool& valid) {
    float t  = (g + 1.0f) * 48.0f;
    float ix = (t - 1.0f) * 0.5f;
    float r  = rintf(ix);          // round half to even
    int   i  = (int)r;
    if (i < 0 || i > 47) valid = false;
    return i < 0 ? 0 : (i > 47 ? 47 : i);
}

// ---------------------------------------------------------------------------
// Weight pre-pack. hi = f16 RNE(w), lo = f16(w - (f32)hi) (subnormal-capable).
// Hidden layers: 32x32x16 A-frag mapping. L4: 16x16x32 mapping (rows 0..2).
// ---------------------------------------------------------------------------
extern "C" __global__ void __launch_bounds__(256)
pack_w(const float* __restrict__ W0, const float* __restrict__ W1,
       const float* __restrict__ W2, const float* __restrict__ W3,
       const float* __restrict__ W4, u32* __restrict__ ws) {
    int gid = blockIdx.x * 256 + threadIdx.x;   // 0..112639
    const float* W; int NS, K, oh, ol, rem; bool isW4 = false;
    if (gid < 12288)       { W = W0; NS = 6;  K = 71;  oh = O0H; ol = O0L; rem = gid; }
    else if (gid < 45056)  { W = W1; NS = 16; K = 256; oh = O1H; ol = O1L; rem = gid - 12288; }
    else if (gid < 77824)  { W = W2; NS = 16; K = 256; oh = O2H; ol = O2L; rem = gid - 45056; }
    else if (gid < 110592) { W = W3; NS = 16; K = 256; oh = O3H; ol = O3L; rem = gid - 77824; }
    else                   { W = W4; NS = 8;  K = 256; oh = O4H; ol = O4L; rem = gid - 110592; isW4 = true; }
    int i = rem & 3, lane = (rem >> 2) & 63, ts = rem >> 8;
    int s = ts % NS, t = ts / NS;
    float w0, w1;
    if (isW4) {
        int jp = lane & 15;                          // t == 0
        int k0 = s * 32 + (lane >> 4) * 8 + 2 * i;   // 16x16x32 frag
        w0 = (jp < 3 && k0 < K)     ? W[(size_t)k0 * 3 + jp]       : 0.0f;
        w1 = (jp < 3 && k0 + 1 < K) ? W[(size_t)(k0 + 1) * 3 + jp] : 0.0f;
    } else {
        int jp = t * 32 + (lane & 31);               // 32x32x16 frag
        int k0 = s * 16 + (lane >> 5) * 8 + 2 * i;
        w0 = (k0 < K)     ? W[(size_t)k0 * HID + jp]       : 0.0f;
        w1 = (k0 + 1 < K) ? W[(size_t)(k0 + 1) * HID + jp] : 0.0f;
    }
    _Float16 h0 = (_Float16)w0, h1 = (_Float16)w1;        // RNE
    _Float16 l0 = (_Float16)(w0 - (float)h0);
    _Float16 l1 = (_Float16)(w1 - (float)h1);
    ws[oh + rem] = (u32)__builtin_bit_cast(u16, h0) | ((u32)__builtin_bit_cast(u16, h1) << 16);
    ws[ol + rem] = (u32)__builtin_bit_cast(u16, l0) | ((u32)__builtin_bit_cast(u16, l1) << 16);
}

// ---------------------------------------------------------------------------
// One 32x32x16 MFMA MLP layer: act' = relu(W^T · act + b), act f16 in LDS.
// LDS: [128 rows(px)][32 units(16B = 8 f16)], swizzle unit' = u ^ (px & 31).
// Wave owns j' rows wave*32..+31, all 128 px (4 tiles of 32).
// Per s-step(k=16): 1 A-load + 4 B-reads feed 4 MFMAs (x2 if USELO).
// [r14 lesson: halving LDS reads regressed; r13 pipes ~serialized -> cut
//  MFMA-pipe time 17% + halve MFMA instruction count via the 32x32 shape]
// ---------------------------------------------------------------------------
template <int NS, bool USELO>
__device__ __forceinline__ void mfma_layer32(
    const u32* __restrict__ whi, const u32* __restrict__ wlo,
    const float* __restrict__ bias,
    u32* __restrict__ sAct, int wave, int lane) {
    const int col = lane & 31, hi = lane >> 5;
    f32x16 acc[4];
#pragma unroll
    for (int p = 0; p < 4; ++p)
#pragma unroll
        for (int e = 0; e < 16; ++e) acc[p][e] = 0.0f;

#pragma unroll 2
    for (int s = 0; s < NS; ++s) {
        int idx = ((wave * NS + s) * 64 + lane) * 4;
        half8 ah = __builtin_bit_cast(half8, *(const uint4*)(whi + idx));
        half8 al;
        if constexpr (USELO)
            al = __builtin_bit_cast(half8, *(const uint4*)(wlo + idx));
#pragma unroll
        for (int p = 0; p < 4; ++p) {
            int rr = p * 32 + col;
            int u = (s * 2 + hi) ^ (rr & 31);
            half8 bh = __builtin_bit_cast(half8, *(const uint4*)(sAct + rr * 128 + u * 4));
            if constexpr (USELO)
                acc[p] = __builtin_amdgcn_mfma_f32_32x32x16_f16(al, bh, acc[p], 0, 0, 0);
            acc[p] = __builtin_amdgcn_mfma_f32_32x32x16_f16(ah, bh, acc[p], 0, 0, 0);
        }
    }
    __syncthreads();   // all reads of sAct done before overwrite

    // epilogue: bias + relu + f16 pack (RTZ) + LDS write
    // D map: col px = 32p+col, row j' = wave*32 + (e&3) + 8*(e>>2) + 4*hi
#pragma unroll
    for (int grp = 0; grp < 4; ++grp) {
        int jb = wave * 32 + hi * 4 + grp * 8;
        float4 bv = *(const float4*)(bias + jb);
#pragma unroll
        for (int p = 0; p < 4; ++p) {
            float v0 = fmaxf(acc[p][grp * 4 + 0] + bv.x, 0.0f);
            float v1 = fmaxf(acc[p][grp * 4 + 1] + bv.y, 0.0f);
            float v2 = fmaxf(acc[p][grp * 4 + 2] + bv.z, 0.0f);
            float v3 = fmaxf(acc[p][grp * 4 + 3] + bv.w, 0.0f);
            int rr = p * 32 + col;
            int u = (wave * 4 + grp) ^ (rr & 31);
            int a = rr * 128 + u * 4 + hi * 2;
            sAct[a]     = pkrtz(v0, v1);
            sAct[a + 1] = pkrtz(v2, v3);
        }
    }
    __syncthreads();
}

// ---------------------------------------------------------------------------
// Fused LIIF kernel: feature build -> 4 MFMA layers -> MFMA final layer.
// launch_bounds(512,4): cap 128 regs; LDS 64 KB -> 2 blocks/CU.
// ---------------------------------------------------------------------------
extern "C" __global__ void __launch_bounds__(NTHR, 4)
liif_mfma(const float* __restrict__ x, const float* __restrict__ coord,
          const float* __restrict__ cell, const float* __restrict__ lr,
          const float* __restrict__ b0, const float* __restrict__ b1,
          const float* __restrict__ b2, const float* __restrict__ b3,
          const float* __restrict__ b4,
          const u32* __restrict__ ws, float* __restrict__ out) {
    __shared__ u32 sAct[PPB * 128];   // 64 KB
    const int tid = threadIdx.x;
    const int wave = tid >> 6, lane = tid & 63;

    // ---------------- stage 1: 71-dim feature -> LDS f16 --------------------
    // 4 threads per pixel; each loads 16 channels = two 16B units.
    {
        const int px = tid >> 2, sub = tid & 3;
        const int gg = blockIdx.x * PPB + px;
        const int b = gg / (HQ * WQ);
        const float gy = coord[(size_t)gg * 2 + 0];
        const float gx = coord[(size_t)gg * 2 + 1];
        bool vmain = true;
        const int ixn = nearest_idx(gx, vmain);
        const int iyn = nearest_idx(gy, vmain);

        const float* xb = x + (((size_t)b * NC) * HFD + iyn) * HFD + ixn;
        u32 hbuf[8];
#pragma unroll
        for (int e = 0; e < 8; ++e) {
            int c = sub * 16 + e * 2;
            float v0 = vmain ? xb[(size_t)c * (HFD * HFD)] : 0.0f;
            float v1 = vmain ? xb[(size_t)(c + 1) * (HFD * HFD)] : 0.0f;
            hbuf[e] = pkrtz(v0, v1);
        }
        {
            int u = (2 * sub) ^ (px & 31);
            *(uint4*)(sAct + px * 128 + u * 4) = make_uint4(hbuf[0], hbuf[1], hbuf[2], hbuf[3]);
            u = (2 * sub + 1) ^ (px & 31);
            *(uint4*)(sAct + px * 128 + u * 4) = make_uint4(hbuf[4], hbuf[5], hbuf[6], hbuf[7]);
        }
        if (sub == 0) {
            // extras: j = 64..71 -> logical unit 8
            float qyc = vmain ? ((2.0f * (float)iyn + 1.0f) / 48.0f - 1.0f) : 0.0f;
            float qxc = vmain ? ((2.0f * (float)ixn + 1.0f) / 48.0f - 1.0f) : 0.0f;
            float f64v = (gy - qyc) * 48.0f;
            float f65v = (gx - qxc) * 48.0f;
            float f66v = cell[b * 2 + 0] * 48.0f;
            float f67v = cell[b * 2 + 1] * 48.0f;

            // rgb_std over 4 diagonally shifted nearest LR samples (ddof=1)
            const float c148 = (float)(1.0 / 48.0);
            const float LO = (float)(-1.0 + 1e-6);
            const float HI = (float)(1.0 - 1e-6);
            float v[4][3];
#pragma unroll
            for (int a = 0; a < 2; ++a) {
                const float vx = (a == 0) ? -c148 : c148;
#pragma unroll
                for (int qq = 0; qq < 2; ++qq) {
                    const float vy = (qq == 0) ? -c148 : c148;
                    float cy = (gy + vx) + 1e-6f;
                    cy = fminf(fmaxf(cy, LO), HI);
                    float cx = (gx + vy) + 1e-6f;
                    cx = fminf(fmaxf(cx, LO), HI);
                    bool vv = true;
                    int jx = nearest_idx(cx, vv);
                    int jy = nearest_idx(cy, vv);
                    int si = a * 2 + qq;
#pragma unroll
                    for (int ch = 0; ch < 3; ++ch)
                        v[si][ch] = vv ? lr[(((size_t)b * 3 + ch) * HFD + jy) * HFD + jx] : 0.0f;
                }
            }
            float sd[3];
#pragma unroll
            for (int ch = 0; ch < 3; ++ch) {
                float mean = (((v[0][ch] + v[1][ch]) + v[2][ch]) + v[3][ch]) / 4.0f;
                float d0 = v[0][ch] - mean, d1 = v[1][ch] - mean;
                float d2 = v[2][ch] - mean, d3 = v[3][ch] - mean;
                float var = (((d0 * d0 + d1 * d1) + d2 * d2) + d3 * d3) / 3.0f;
                sd[ch] = sqrtf(var);
            }
            int u = 8 ^ (px & 31);
            *(uint4*)(sAct + px * 128 + u * 4) =
                make_uint4(pkrtz(f64v, f65v), pkrtz(f66v, f67v),
                           pkrtz(sd[0], sd[1]), pkrtz(sd[2], 0.0f));
        } else {
            // zero-pad logical units 9..11 (k = 72..95)
            int u = (8 + sub) ^ (px & 31);
            *(uint4*)(sAct + px * 128 + u * 4) = make_uint4(0, 0, 0, 0);
        }
    }
    __syncthreads();

    // ---------------- 4 hidden layers on the matrix pipe (32x32x16) ---------
    mfma_layer32<6,  true >(ws + O0H, ws + O0L, b0, sAct, wave, lane);  // lo anchors input
    mfma_layer32<16, false>(ws + O1H, ws + O1L, b1, sAct, wave, lane);  // f16-only weights
    mfma_layer32<16, false>(ws + O2H, ws + O2L, b2, sAct, wave, lane);
    mfma_layer32<16, false>(ws + O3H, ws + O3L, b3, sAct, wave, lane);

    // ---------------- final 256 -> 3 via 16x16x32 MFMA (hi+lo) --------------
    // Wave w owns px-tile p = w (16 px). D: col px=16w+(lane&15), rows 4g+e;
    // valid outputs o=0..2 live in lanes g==0. Stores coalesced over r.
    {
        const int r = lane & 15, g = lane >> 4;
        const int rr = wave * 16 + r;
        f32x4 acc = f32x4{0.0f, 0.0f, 0.0f, 0.0f};
#pragma unroll
        for (int s = 0; s < 8; ++s) {
            int idx = (s * 64 + lane) * 4;
            half8 ah = __builtin_bit_cast(half8, *(const uint4*)(ws + O4H + idx));
            half8 al = __builtin_bit_cast(half8, *(const uint4*)(ws + O4L + idx));
            int u = (s * 4 + g) ^ (rr & 31);
            half8 bh = __builtin_bit_cast(half8, *(const uint4*)(sAct + rr * 128 + u * 4));
            acc = __builtin_amdgcn_mfma_f32_16x16x32_f16(al, bh, acc, 0, 0, 0);
            acc = __builtin_amdgcn_mfma_f32_16x16x32_f16(ah, bh, acc, 0, 0, 0);
        }
        if (g == 0) {
            int px = wave * 16 + r;
            int gg = blockIdx.x * PPB + px;
            int b = gg / (HQ * WQ);
            int rem = gg - b * (HQ * WQ);
#pragma unroll
            for (int o = 0; o < 3; ++o)
                out[((size_t)(b * 3 + o)) * (HQ * WQ) + rem] = acc[o] + b4[o];
        }
    }
}

extern "C" void kernel_launch(void* const* d_in, const int* in_sizes, int n_in,
                              void* d_out, int out_size, void* d_ws, size_t ws_size,
                              hipStream_t stream) {
    const float* x     = (const float*)d_in[0];
    const float* coord = (const float*)d_in[1];
    const float* cell  = (const float*)d_in[2];
    const float* lr    = (const float*)d_in[3];
    const float* W0    = (const float*)d_in[4];
    const float* b0    = (const float*)d_in[5];
    const float* W1    = (const float*)d_in[6];
    const float* b1    = (const float*)d_in[7];
    const float* W2    = (const float*)d_in[8];
    const float* b2    = (const float*)d_in[9];
    const float* W3    = (const float*)d_in[10];
    const float* b3    = (const float*)d_in[11];
    const float* W4    = (const float*)d_in[12];
    const float* b4    = (const float*)d_in[13];
    u32* ws = (u32*)d_ws;

    pack_w<<<dim3(440), dim3(256), 0, stream>>>(W0, W1, W2, W3, W4, ws);
    liif_mfma<<<dim3(NPIX / PPB), dim3(NTHR), 0, stream>>>(
        x, coord, cell, lr, b0, b1, b2, b3, b4, ws, (float*)d_out);
}

// Round 16
// 419.716 us; speedup vs baseline: 1.0703x; 1.0703x over previous
//
#include <hip/hip_runtime.h>

#pragma clang fp contract(off)

#define HQ 384
#define WQ 384
#define NC 64
#define HFD 48
#define HID 256
#define NPIX (4 * HQ * WQ)
#define PPB 128  // pixels per block
#define NTHR 512 // 8 waves; each wave owns 2 j'-tiles x 8 px-tiles

typedef _Float16 half8 __attribute__((ext_vector_type(8)));
typedef __fp16 fp16x2 __attribute__((ext_vector_type(2)));   // cvt_pkrtz native type
typedef float f32x4 __attribute__((ext_vector_type(4)));
typedef unsigned int u32;
typedef unsigned short u16;

// ws layout in u32 units: per layer, A=W^T fragments, hi then lo(residual).
// entry index = ((T*NS + s)*64 + lane)*4 + i ; L0: NT=16,NS=3 ; L1-3: NT=16,NS=8
// L4 (final 256->3): NT=1 (rows 0..2 valid, rest zero), NS=8.
#define O0H 0
#define O0L 12288
#define O1H 24576
#define O1L 57344
#define O2H 90112
#define O2L 122880
#define O3H 155648
#define O3L 188416
#define O4H 221184
#define O4L 223232
// total 225280 u32 = 901120 bytes of d_ws used

__device__ __forceinline__ u32 pkrtz(float a, float b) {
    fp16x2 h = __builtin_amdgcn_cvt_pkrtz(a, b);   // v_cvt_pkrtz_f16_f32
    return __builtin_bit_cast(u32, h);
}

// ---------------------------------------------------------------------------
// Nearest-sample index per grid_sample(nearest, align_corners=False).
// Exact f32 op sequence (contraction off file-wide). Validated on HW (r3/r5).
// ---------------------------------------------------------------------------
__device__ __forceinline__ int nearest_idx(float g, bool& valid) {
    float t  = (g + 1.0f) * 48.0f;
    float ix = (t - 1.0f) * 0.5f;
    float r  = rintf(ix);          // round half to even
    int   i  = (int)r;
    if (i < 0 || i > 47) valid = false;
    return i < 0 ? 0 : (i > 47 ? 47 : i);
}

// ---------------------------------------------------------------------------
// Weight pre-pack: A = W^T as MFMA A-fragments. hi = f16 RNE(w),
// lo = f16(w - (f32)hi) UNSCALED (subnormal-capable) -> accumulates directly.
// lane: row j' = 16t + (lane&15), k = 32s + 8*(lane>>4) + 2i (+1)
// W4 ([256][3]) packed transposed into rows 0..2 of a single tile.
// ---------------------------------------------------------------------------
extern "C" __global__ void __launch_bounds__(256)
pack_w(const float* __restrict__ W0, const float* __restrict__ W1,
       const float* __restrict__ W2, const float* __restrict__ W3,
       const float* __restrict__ W4, u32* __restrict__ ws) {
    int gid = blockIdx.x * 256 + threadIdx.x;   // 0..112639
    const float* W; int NS, K, oh, ol, rem; bool isW4 = false;
    if (gid < 12288)       { W = W0; NS = 3; K = 71;  oh = O0H; ol = O0L; rem = gid; }
    else if (gid < 45056)  { W = W1; NS = 8; K = 256; oh = O1H; ol = O1L; rem = gid - 12288; }
    else if (gid < 77824)  { W = W2; NS = 8; K = 256; oh = O2H; ol = O2L; rem = gid - 45056; }
    else if (gid < 110592) { W = W3; NS = 8; K = 256; oh = O3H; ol = O3L; rem = gid - 77824; }
    else                   { W = W4; NS = 8; K = 256; oh = O4H; ol = O4L; rem = gid - 110592; isW4 = true; }
    int i = rem & 3, lane = (rem >> 2) & 63, ts = rem >> 8;
    int s = ts % NS, t = ts / NS;
    int jp = t * 16 + (lane & 15);
    int k0 = s * 32 + (lane >> 4) * 8 + 2 * i;
    float w0, w1;
    if (isW4) {
        w0 = (jp < 3 && k0 < K)     ? W[(size_t)k0 * 3 + jp]       : 0.0f;
        w1 = (jp < 3 && k0 + 1 < K) ? W[(size_t)(k0 + 1) * 3 + jp] : 0.0f;
    } else {
        w0 = (k0 < K)     ? W[(size_t)k0 * HID + jp]       : 0.0f;
        w1 = (k0 + 1 < K) ? W[(size_t)(k0 + 1) * HID + jp] : 0.0f;
    }
    _Float16 h0 = (_Float16)w0, h1 = (_Float16)w1;        // RNE
    _Float16 l0 = (_Float16)(w0 - (float)h0);
    _Float16 l1 = (_Float16)(w1 - (float)h1);
    ws[oh + rem] = (u32)__builtin_bit_cast(u16, h0) | ((u32)__builtin_bit_cast(u16, h1) << 16);
    ws[ol + rem] = (u32)__builtin_bit_cast(u16, l0) | ((u32)__builtin_bit_cast(u16, l1) << 16);
}

// ---------------------------------------------------------------------------
// One MFMA MLP layer: act' = relu(W^T · act + b), act in LDS as f16 (hi only).
// LDS: [128 rows(px)][32 units(16B = 8 f16)], swizzle unit' = u ^ (px & 31).
// 8 waves; wave owns 2 j'-tiles (T = wave*2+tt) x all 8 px-tiles.
// [r12 structure = best measured (369us); r14 px-halved and r15 32x32-shape
//  both regressed -> 16 independent acc chains + this load balance is the
//  sweet spot. T5 setprio added r16: MFMA cluster wrapped.]
// ---------------------------------------------------------------------------
template <int NS, bool USELO>
__device__ __forceinline__ void mfma_layer(
    const u32* __restrict__ whi, const u32* __restrict__ wlo,
    const float* __restrict__ bias,
    u32* __restrict__ sAct, int wave, int lane) {
    const int r = lane & 15, g = lane >> 4;
    f32x4 acc[2][8];
#pragma unroll
    for (int a = 0; a < 2; ++a)
#pragma unroll
        for (int b = 0; b < 8; ++b) acc[a][b] = f32x4{0.0f, 0.0f, 0.0f, 0.0f};

    auto sstep = [&](int s) {
        half8 ah[2], al[2];
#pragma unroll
        for (int tt = 0; tt < 2; ++tt) {
            int idx = (((wave * 2 + tt) * NS + s) * 64 + lane) * 4;
            ah[tt] = __builtin_bit_cast(half8, *(const uint4*)(whi + idx));
            if constexpr (USELO)
                al[tt] = __builtin_bit_cast(half8, *(const uint4*)(wlo + idx));
        }
#pragma unroll
        for (int p = 0; p < 8; ++p) {
            int rr = p * 16 + r;
            int u = (s * 4 + g) ^ (rr & 31);
            half8 bh = __builtin_bit_cast(half8, *(const uint4*)(sAct + rr * 128 + u * 4));
            __builtin_amdgcn_s_setprio(1);
#pragma unroll
            for (int tt = 0; tt < 2; ++tt) {
                if constexpr (USELO)
                    acc[tt][p] = __builtin_amdgcn_mfma_f32_16x16x32_f16(al[tt], bh, acc[tt][p], 0, 0, 0);
                acc[tt][p] = __builtin_amdgcn_mfma_f32_16x16x32_f16(ah[tt], bh, acc[tt][p], 0, 0, 0);
            }
            __builtin_amdgcn_s_setprio(0);
        }
    };
    if constexpr (USELO) {
#pragma unroll 2
        for (int s = 0; s < NS; ++s) sstep(s);
    } else {
#pragma unroll 4
        for (int s = 0; s < NS; ++s) sstep(s);
    }
    __syncthreads();   // all reads of sAct done before overwrite

    // epilogue: bias + relu + f16 pack (RTZ, 1 inst / 2 vals) + LDS write
    // D mapping: col px = 16p + (lane&15), row j' = 16T + 4g + e
#pragma unroll
    for (int tt = 0; tt < 2; ++tt) {
        int T = wave * 2 + tt;
        int jb = T * 16 + g * 4;
        float bv0 = bias[jb + 0], bv1 = bias[jb + 1];
        float bv2 = bias[jb + 2], bv3 = bias[jb + 3];
#pragma unroll
        for (int p = 0; p < 8; ++p) {
            float v0 = fmaxf(acc[tt][p][0] + bv0, 0.0f);
            float v1 = fmaxf(acc[tt][p][1] + bv1, 0.0f);
            float v2 = fmaxf(acc[tt][p][2] + bv2, 0.0f);
            float v3 = fmaxf(acc[tt][p][3] + bv3, 0.0f);
            int rr = p * 16 + r;
            int u = (2 * T + (g >> 1)) ^ (rr & 31);
            int a = rr * 128 + u * 4 + (g & 1) * 2;
            sAct[a]     = pkrtz(v0, v1);
            sAct[a + 1] = pkrtz(v2, v3);
        }
    }
    __syncthreads();
}

// ---------------------------------------------------------------------------
// Fused LIIF kernel: feature build -> 4 MFMA layers -> MFMA final layer.
// launch_bounds(512,4): cap 128 regs; LDS 64 KB -> 2 blocks/CU.
// ---------------------------------------------------------------------------
extern "C" __global__ void __launch_bounds__(NTHR, 4)
liif_mfma(const float* __restrict__ x, const float* __restrict__ coord,
          const float* __restrict__ cell, const float* __restrict__ lr,
          const float* __restrict__ b0, const float* __restrict__ b1,
          const float* __restrict__ b2, const float* __restrict__ b3,
          const float* __restrict__ b4,
          const u32* __restrict__ ws, float* __restrict__ out) {
    __shared__ u32 sAct[PPB * 128];   // 64 KB
    const int tid = threadIdx.x;
    const int wave = tid >> 6, lane = tid & 63;

    // ---------------- stage 1: 71-dim feature -> LDS f16 --------------------
    // 4 threads per pixel; each loads 16 channels = two 16B units.
    {
        const int px = tid >> 2, sub = tid & 3;
        const int gg = blockIdx.x * PPB + px;
        const int b = gg / (HQ * WQ);
        const float gy = coord[(size_t)gg * 2 + 0];
        const float gx = coord[(size_t)gg * 2 + 1];
        bool vmain = true;
        const int ixn = nearest_idx(gx, vmain);
        const int iyn = nearest_idx(gy, vmain);

        const float* xb = x + (((size_t)b * NC) * HFD + iyn) * HFD + ixn;
        u32 hbuf[8];
#pragma unroll
        for (int e = 0; e < 8; ++e) {
            int c = sub * 16 + e * 2;
            float v0 = vmain ? xb[(size_t)c * (HFD * HFD)] : 0.0f;
            float v1 = vmain ? xb[(size_t)(c + 1) * (HFD * HFD)] : 0.0f;
            hbuf[e] = pkrtz(v0, v1);
        }
        {
            int u = (2 * sub) ^ (px & 31);
            *(uint4*)(sAct + px * 128 + u * 4) = make_uint4(hbuf[0], hbuf[1], hbuf[2], hbuf[3]);
            u = (2 * sub + 1) ^ (px & 31);
            *(uint4*)(sAct + px * 128 + u * 4) = make_uint4(hbuf[4], hbuf[5], hbuf[6], hbuf[7]);
        }
        if (sub == 0) {
            // extras: j = 64..71 -> logical unit 8
            float qyc = vmain ? ((2.0f * (float)iyn + 1.0f) / 48.0f - 1.0f) : 0.0f;
            float qxc = vmain ? ((2.0f * (float)ixn + 1.0f) / 48.0f - 1.0f) : 0.0f;
            float f64v = (gy - qyc) * 48.0f;
            float f65v = (gx - qxc) * 48.0f;
            float f66v = cell[b * 2 + 0] * 48.0f;
            float f67v = cell[b * 2 + 1] * 48.0f;

            // rgb_std over 4 diagonally shifted nearest LR samples (ddof=1)
            const float c148 = (float)(1.0 / 48.0);
            const float LO = (float)(-1.0 + 1e-6);
            const float HI = (float)(1.0 - 1e-6);
            float v[4][3];
#pragma unroll
            for (int a = 0; a < 2; ++a) {
                const float vx = (a == 0) ? -c148 : c148;
#pragma unroll
                for (int qq = 0; qq < 2; ++qq) {
                    const float vy = (qq == 0) ? -c148 : c148;
                    float cy = (gy + vx) + 1e-6f;
                    cy = fminf(fmaxf(cy, LO), HI);
                    float cx = (gx + vy) + 1e-6f;
                    cx = fminf(fmaxf(cx, LO), HI);
                    bool vv = true;
                    int jx = nearest_idx(cx, vv);
                    int jy = nearest_idx(cy, vv);
                    int si = a * 2 + qq;
#pragma unroll
                    for (int ch = 0; ch < 3; ++ch)
                        v[si][ch] = vv ? lr[(((size_t)b * 3 + ch) * HFD + jy) * HFD + jx] : 0.0f;
                }
            }
            float sd[3];
#pragma unroll
            for (int ch = 0; ch < 3; ++ch) {
                float mean = (((v[0][ch] + v[1][ch]) + v[2][ch]) + v[3][ch]) / 4.0f;
                float d0 = v[0][ch] - mean, d1 = v[1][ch] - mean;
                float d2 = v[2][ch] - mean, d3 = v[3][ch] - mean;
                float var = (((d0 * d0 + d1 * d1) + d2 * d2) + d3 * d3) / 3.0f;
                sd[ch] = sqrtf(var);
            }
            int u = 8 ^ (px & 31);
            *(uint4*)(sAct + px * 128 + u * 4) =
                make_uint4(pkrtz(f64v, f65v), pkrtz(f66v, f67v),
                           pkrtz(sd[0], sd[1]), pkrtz(sd[2], 0.0f));
        } else {
            // zero-pad logical units 9..11 (k = 72..95)
            int u = (8 + sub) ^ (px & 31);
            *(uint4*)(sAct + px * 128 + u * 4) = make_uint4(0, 0, 0, 0);
        }
    }
    __syncthreads();

    // ---------------- 4 hidden layers on the matrix pipe --------------------
    mfma_layer<3, true >(ws + O0H, ws + O0L, b0, sAct, wave, lane);  // lo kept: anchors input
    mfma_layer<8, false>(ws + O1H, ws + O1L, b1, sAct, wave, lane);  // f16-only weights
    mfma_layer<8, false>(ws + O2H, ws + O2L, b2, sAct, wave, lane);
    mfma_layer<8, false>(ws + O3H, ws + O3L, b3, sAct, wave, lane);

    // ---------------- final 256 -> 3 via MFMA (hi+lo, 16 MFMA/wave) ---------
    // Wave w owns px-tile p = w (16 px). D: col px=16w+(lane&15), rows 4g+e;
    // valid outputs o=0..2 live in lanes g==0. Stores coalesced over r.
    {
        const int r = lane & 15, g = lane >> 4;
        const int rr = wave * 16 + r;
        f32x4 acc = f32x4{0.0f, 0.0f, 0.0f, 0.0f};
#pragma unroll
        for (int s = 0; s < 8; ++s) {
            int idx = (s * 64 + lane) * 4;
            half8 ah = __builtin_bit_cast(half8, *(const uint4*)(ws + O4H + idx));
            half8 al = __builtin_bit_cast(half8, *(const uint4*)(ws + O4L + idx));
            int u = (s * 4 + g) ^ (rr & 31);
            half8 bh = __builtin_bit_cast(half8, *(const uint4*)(sAct + rr * 128 + u * 4));
            __builtin_amdgcn_s_setprio(1);
            acc = __builtin_amdgcn_mfma_f32_16x16x32_f16(al, bh, acc, 0, 0, 0);
            acc = __builtin_amdgcn_mfma_f32_16x16x32_f16(ah, bh, acc, 0, 0, 0);
            __builtin_amdgcn_s_setprio(0);
        }
        if (g == 0) {
            int px = wave * 16 + r;
            int gg = blockIdx.x * PPB + px;
            int b = gg / (HQ * WQ);
            int rem = gg - b * (HQ * WQ);
#pragma unroll
            for (int o = 0; o < 3; ++o)
                out[((size_t)(b * 3 + o)) * (HQ * WQ) + rem] = acc[o] + b4[o];
        }
    }
}

extern "C" void kernel_launch(void* const* d_in, const int* in_sizes, int n_in,
                              void* d_out, int out_size, void* d_ws, size_t ws_size,
                              hipStream_t stream) {
    const float* x     = (const float*)d_in[0];
    const float* coord = (const float*)d_in[1];
    const float* cell  = (const float*)d_in[2];
    const float* lr    = (const float*)d_in[3];
    const float* W0    = (const float*)d_in[4];
    const float* b0    = (const float*)d_in[5];
    const float* W1    = (const float*)d_in[6];
    const float* b1    = (const float*)d_in[7];
    const float* W2    = (const float*)d_in[8];
    const float* b2    = (const float*)d_in[9];
    const float* W3    = (const float*)d_in[10];
    const float* b3    = (const float*)d_in[11];
    const float* W4    = (const float*)d_in[12];
    const float* b4    = (const float*)d_in[13];
    u32* ws = (u32*)d_ws;

    pack_w<<<dim3(440), dim3(256), 0, stream>>>(W0, W1, W2, W3, W4, ws);
    liif_mfma<<<dim3(NPIX / PPB), dim3(NTHR), 0, stream>>>(
        x, coord, cell, lr, b0, b1, b2, b3, b4, ws, (float*)d_out);
}

// Round 17
// 395.192 us; speedup vs baseline: 1.1368x; 1.0621x over previous
//
#include <hip/hip_runtime.h>

#pragma clang fp contract(off)

#define HQ 384
#define WQ 384
#define NC 64
#define HFD 48
#define HID 256
#define NPIX (4 * HQ * WQ)
#define PPB 128  // pixels per block
#define NTHR 512 // 8 waves; each wave owns 2 j'-tiles x 8 px-tiles

typedef _Float16 half8 __attribute__((ext_vector_type(8)));
typedef __fp16 fp16x2 __attribute__((ext_vector_type(2)));   // cvt_pkrtz native type
typedef float f32x4 __attribute__((ext_vector_type(4)));
typedef unsigned int u32;
typedef unsigned short u16;

// ws layout in u32 units: per layer, A=W^T fragments, hi then lo(residual).
// entry index = ((T*NS + s)*64 + lane)*4 + i ; L0: NT=16,NS=3 ; L1-3: NT=16,NS=8
// L4 (final 256->3): NT=1 (rows 0..2 valid, rest zero), NS=8.
#define O0H 0
#define O0L 12288
#define O1H 24576
#define O1L 57344
#define O2H 90112
#define O2L 122880
#define O3H 155648
#define O3L 188416
#define O4H 221184
#define O4L 223232
// total 225280 u32 = 901120 bytes of d_ws used

__device__ __forceinline__ u32 pkrtz(float a, float b) {
    fp16x2 h = __builtin_amdgcn_cvt_pkrtz(a, b);   // v_cvt_pkrtz_f16_f32
    return __builtin_bit_cast(u32, h);
}

// ---------------------------------------------------------------------------
// Nearest-sample index per grid_sample(nearest, align_corners=False).
// Exact f32 op sequence (contraction off file-wide). Validated on HW (r3/r5).
// ---------------------------------------------------------------------------
__device__ __forceinline__ int nearest_idx(float g, bool& valid) {
    float t  = (g + 1.0f) * 48.0f;
    float ix = (t - 1.0f) * 0.5f;
    float r  = rintf(ix);          // round half to even
    int   i  = (int)r;
    if (i < 0 || i > 47) valid = false;
    return i < 0 ? 0 : (i > 47 ? 47 : i);
}

// ---------------------------------------------------------------------------
// Weight pre-pack: A = W^T as MFMA A-fragments. hi = f16 RNE(w),
// lo = f16(w - (f32)hi) UNSCALED (subnormal-capable) -> accumulates directly.
// lane: row j' = 16t + (lane&15), k = 32s + 8*(lane>>4) + 2i (+1)
// W4 ([256][3]) packed transposed into rows 0..2 of a single tile.
// ---------------------------------------------------------------------------
extern "C" __global__ void __launch_bounds__(256)
pack_w(const float* __restrict__ W0, const float* __restrict__ W1,
       const float* __restrict__ W2, const float* __restrict__ W3,
       const float* __restrict__ W4, u32* __restrict__ ws) {
    int gid = blockIdx.x * 256 + threadIdx.x;   // 0..112639
    const float* W; int NS, K, oh, ol, rem; bool isW4 = false;
    if (gid < 12288)       { W = W0; NS = 3; K = 71;  oh = O0H; ol = O0L; rem = gid; }
    else if (gid < 45056)  { W = W1; NS = 8; K = 256; oh = O1H; ol = O1L; rem = gid - 12288; }
    else if (gid < 77824)  { W = W2; NS = 8; K = 256; oh = O2H; ol = O2L; rem = gid - 45056; }
    else if (gid < 110592) { W = W3; NS = 8; K = 256; oh = O3H; ol = O3L; rem = gid - 77824; }
    else                   { W = W4; NS = 8; K = 256; oh = O4H; ol = O4L; rem = gid - 110592; isW4 = true; }
    int i = rem & 3, lane = (rem >> 2) & 63, ts = rem >> 8;
    int s = ts % NS, t = ts / NS;
    int jp = t * 16 + (lane & 15);
    int k0 = s * 32 + (lane >> 4) * 8 + 2 * i;
    float w0, w1;
    if (isW4) {
        w0 = (jp < 3 && k0 < K)     ? W[(size_t)k0 * 3 + jp]       : 0.0f;
        w1 = (jp < 3 && k0 + 1 < K) ? W[(size_t)(k0 + 1) * 3 + jp] : 0.0f;
    } else {
        w0 = (k0 < K)     ? W[(size_t)k0 * HID + jp]       : 0.0f;
        w1 = (k0 + 1 < K) ? W[(size_t)(k0 + 1) * HID + jp] : 0.0f;
    }
    _Float16 h0 = (_Float16)w0, h1 = (_Float16)w1;        // RNE
    _Float16 l0 = (_Float16)(w0 - (float)h0);
    _Float16 l1 = (_Float16)(w1 - (float)h1);
    ws[oh + rem] = (u32)__builtin_bit_cast(u16, h0) | ((u32)__builtin_bit_cast(u16, h1) << 16);
    ws[ol + rem] = (u32)__builtin_bit_cast(u16, l0) | ((u32)__builtin_bit_cast(u16, l1) << 16);
}

// ---------------------------------------------------------------------------
// One MFMA MLP layer: act' = relu(W^T · act + b), act in LDS as f16 (hi only).
// LDS: [128 rows(px)][32 units(16B = 8 f16)], swizzle unit' = u ^ (px & 31).
// 8 waves; wave owns 2 j'-tiles (T = wave*2+tt) x all 8 px-tiles.
// [r12/r13 structure = measured optimum. Falsified alternatives: r9 occupancy
//  +44%->+0%; r14 px-halved -6%; r15 32x32-shape -10%; r16 setprio -4%.]
// ---------------------------------------------------------------------------
template <int NS, bool USELO>
__device__ __forceinline__ void mfma_layer(
    const u32* __restrict__ whi, const u32* __restrict__ wlo,
    const float* __restrict__ bias,
    u32* __restrict__ sAct, int wave, int lane) {
    const int r = lane & 15, g = lane >> 4;
    f32x4 acc[2][8];
#pragma unroll
    for (int a = 0; a < 2; ++a)
#pragma unroll
        for (int b = 0; b < 8; ++b) acc[a][b] = f32x4{0.0f, 0.0f, 0.0f, 0.0f};

    auto sstep = [&](int s) {
        half8 ah[2], al[2];
#pragma unroll
        for (int tt = 0; tt < 2; ++tt) {
            int idx = (((wave * 2 + tt) * NS + s) * 64 + lane) * 4;
            ah[tt] = __builtin_bit_cast(half8, *(const uint4*)(whi + idx));
            if constexpr (USELO)
                al[tt] = __builtin_bit_cast(half8, *(const uint4*)(wlo + idx));
        }
#pragma unroll
        for (int p = 0; p < 8; ++p) {
            int rr = p * 16 + r;
            int u = (s * 4 + g) ^ (rr & 31);
            half8 bh = __builtin_bit_cast(half8, *(const uint4*)(sAct + rr * 128 + u * 4));
#pragma unroll
            for (int tt = 0; tt < 2; ++tt) {
                if constexpr (USELO)
                    acc[tt][p] = __builtin_amdgcn_mfma_f32_16x16x32_f16(al[tt], bh, acc[tt][p], 0, 0, 0);
                acc[tt][p] = __builtin_amdgcn_mfma_f32_16x16x32_f16(ah[tt], bh, acc[tt][p], 0, 0, 0);
            }
        }
    };
    if constexpr (USELO) {
#pragma unroll 2
        for (int s = 0; s < NS; ++s) sstep(s);
    } else {
#pragma unroll 4
        for (int s = 0; s < NS; ++s) sstep(s);
    }
    __syncthreads();   // all reads of sAct done before overwrite

    // epilogue: bias + relu + f16 pack (RTZ) + single b64 LDS write per p
    // D mapping: col px = 16p + (lane&15), row j' = 16T + 4g + e
#pragma unroll
    for (int tt = 0; tt < 2; ++tt) {
        int T = wave * 2 + tt;
        int jb = T * 16 + g * 4;
        float bv0 = bias[jb + 0], bv1 = bias[jb + 1];
        float bv2 = bias[jb + 2], bv3 = bias[jb + 3];
#pragma unroll
        for (int p = 0; p < 8; ++p) {
            float v0 = fmaxf(acc[tt][p][0] + bv0, 0.0f);
            float v1 = fmaxf(acc[tt][p][1] + bv1, 0.0f);
            float v2 = fmaxf(acc[tt][p][2] + bv2, 0.0f);
            float v3 = fmaxf(acc[tt][p][3] + bv3, 0.0f);
            int rr = p * 16 + r;
            int u = (2 * T + (g >> 1)) ^ (rr & 31);
            int a = rr * 128 + u * 4 + (g & 1) * 2;   // 8B-aligned
            *(uint2*)(sAct + a) = make_uint2(pkrtz(v0, v1), pkrtz(v2, v3));
        }
    }
    __syncthreads();
}

// ---------------------------------------------------------------------------
// Fused LIIF kernel: feature build -> 4 MFMA layers -> MFMA final layer.
// launch_bounds(512,4): cap 128 regs; LDS 64 KB -> 2 blocks/CU.
// ---------------------------------------------------------------------------
extern "C" __global__ void __launch_bounds__(NTHR, 4)
liif_mfma(const float* __restrict__ x, const float* __restrict__ coord,
          const float* __restrict__ cell, const float* __restrict__ lr,
          const float* __restrict__ b0, const float* __restrict__ b1,
          const float* __restrict__ b2, const float* __restrict__ b3,
          const float* __restrict__ b4,
          const u32* __restrict__ ws, float* __restrict__ out) {
    __shared__ u32 sAct[PPB * 128];   // 64 KB
    const int tid = threadIdx.x;
    const int wave = tid >> 6, lane = tid & 63;

    // ---------------- stage 1: 71-dim feature -> LDS f16 --------------------
    // 4 threads per pixel; each loads 16 channels = two 16B units.
    {
        const int px = tid >> 2, sub = tid & 3;
        const int gg = blockIdx.x * PPB + px;
        const int b = gg / (HQ * WQ);
        const float gy = coord[(size_t)gg * 2 + 0];
        const float gx = coord[(size_t)gg * 2 + 1];
        bool vmain = true;
        const int ixn = nearest_idx(gx, vmain);
        const int iyn = nearest_idx(gy, vmain);

        const float* xb = x + (((size_t)b * NC) * HFD + iyn) * HFD + ixn;
        u32 hbuf[8];
#pragma unroll
        for (int e = 0; e < 8; ++e) {
            int c = sub * 16 + e * 2;
            float v0 = vmain ? xb[(size_t)c * (HFD * HFD)] : 0.0f;
            float v1 = vmain ? xb[(size_t)(c + 1) * (HFD * HFD)] : 0.0f;
            hbuf[e] = pkrtz(v0, v1);
        }
        {
            int u = (2 * sub) ^ (px & 31);
            *(uint4*)(sAct + px * 128 + u * 4) = make_uint4(hbuf[0], hbuf[1], hbuf[2], hbuf[3]);
            u = (2 * sub + 1) ^ (px & 31);
            *(uint4*)(sAct + px * 128 + u * 4) = make_uint4(hbuf[4], hbuf[5], hbuf[6], hbuf[7]);
        }
        if (sub == 0) {
            // extras: j = 64..71 -> logical unit 8
            float qyc = vmain ? ((2.0f * (float)iyn + 1.0f) / 48.0f - 1.0f) : 0.0f;
            float qxc = vmain ? ((2.0f * (float)ixn + 1.0f) / 48.0f - 1.0f) : 0.0f;
            float f64v = (gy - qyc) * 48.0f;
            float f65v = (gx - qxc) * 48.0f;
            float f66v = cell[b * 2 + 0] * 48.0f;
            float f67v = cell[b * 2 + 1] * 48.0f;

            // rgb_std over 4 diagonally shifted nearest LR samples (ddof=1)
            const float c148 = (float)(1.0 / 48.0);
            const float LO = (float)(-1.0 + 1e-6);
            const float HI = (float)(1.0 - 1e-6);
            float v[4][3];
#pragma unroll
            for (int a = 0; a < 2; ++a) {
                const float vx = (a == 0) ? -c148 : c148;
#pragma unroll
                for (int qq = 0; qq < 2; ++qq) {
                    const float vy = (qq == 0) ? -c148 : c148;
                    float cy = (gy + vx) + 1e-6f;
                    cy = fminf(fmaxf(cy, LO), HI);
                    float cx = (gx + vy) + 1e-6f;
                    cx = fminf(fmaxf(cx, LO), HI);
                    bool vv = true;
                    int jx = nearest_idx(cx, vv);
                    int jy = nearest_idx(cy, vv);
                    int si = a * 2 + qq;
#pragma unroll
                    for (int ch = 0; ch < 3; ++ch)
                        v[si][ch] = vv ? lr[(((size_t)b * 3 + ch) * HFD + jy) * HFD + jx] : 0.0f;
                }
            }
            float sd[3];
#pragma unroll
            for (int ch = 0; ch < 3; ++ch) {
                float mean = (((v[0][ch] + v[1][ch]) + v[2][ch]) + v[3][ch]) / 4.0f;
                float d0 = v[0][ch] - mean, d1 = v[1][ch] - mean;
                float d2 = v[2][ch] - mean, d3 = v[3][ch] - mean;
                float var = (((d0 * d0 + d1 * d1) + d2 * d2) + d3 * d3) / 3.0f;
                sd[ch] = sqrtf(var);
            }
            int u = 8 ^ (px & 31);
            *(uint4*)(sAct + px * 128 + u * 4) =
                make_uint4(pkrtz(f64v, f65v), pkrtz(f66v, f67v),
                           pkrtz(sd[0], sd[1]), pkrtz(sd[2], 0.0f));
        } else {
            // zero-pad logical units 9..11 (k = 72..95)
            int u = (8 + sub) ^ (px & 31);
            *(uint4*)(sAct + px * 128 + u * 4) = make_uint4(0, 0, 0, 0);
        }
    }
    __syncthreads();

    // ---------------- 4 hidden layers on the matrix pipe --------------------
    mfma_layer<3, true >(ws + O0H, ws + O0L, b0, sAct, wave, lane);  // lo kept: anchors input
    mfma_layer<8, false>(ws + O1H, ws + O1L, b1, sAct, wave, lane);  // f16-only weights
    mfma_layer<8, false>(ws + O2H, ws + O2L, b2, sAct, wave, lane);
    mfma_layer<8, false>(ws + O3H, ws + O3L, b3, sAct, wave, lane);

    // ---------------- final 256 -> 3 via MFMA (hi+lo, 16 MFMA/wave) ---------
    // Wave w owns px-tile p = w (16 px). D: col px=16w+(lane&15), rows 4g+e;
    // valid outputs o=0..2 live in lanes g==0. Stores coalesced over r.
    {
        const int r = lane & 15, g = lane >> 4;
        const int rr = wave * 16 + r;
        f32x4 acc = f32x4{0.0f, 0.0f, 0.0f, 0.0f};
#pragma unroll
        for (int s = 0; s < 8; ++s) {
            int idx = (s * 64 + lane) * 4;
            half8 ah = __builtin_bit_cast(half8, *(const uint4*)(ws + O4H + idx));
            half8 al = __builtin_bit_cast(half8, *(const uint4*)(ws + O4L + idx));
            int u = (s * 4 + g) ^ (rr & 31);
            half8 bh = __builtin_bit_cast(half8, *(const uint4*)(sAct + rr * 128 + u * 4));
            acc = __builtin_amdgcn_mfma_f32_16x16x32_f16(al, bh, acc, 0, 0, 0);
            acc = __builtin_amdgcn_mfma_f32_16x16x32_f16(ah, bh, acc, 0, 0, 0);
        }
        if (g == 0) {
            int px = wave * 16 + r;
            int gg = blockIdx.x * PPB + px;
            int b = gg / (HQ * WQ);
            int rem = gg - b * (HQ * WQ);
#pragma unroll
            for (int o = 0; o < 3; ++o)
                out[((size_t)(b * 3 + o)) * (HQ * WQ) + rem] = acc[o] + b4[o];
        }
    }
}

extern "C" void kernel_launch(void* const* d_in, const int* in_sizes, int n_in,
                              void* d_out, int out_size, void* d_ws, size_t ws_size,
                              hipStream_t stream) {
    const float* x     = (const float*)d_in[0];
    const float* coord = (const float*)d_in[1];
    const float* cell  = (const float*)d_in[2];
    const float* lr    = (const float*)d_in[3];
    const float* W0    = (const float*)d_in[4];
    const float* b0    = (const float*)d_in[5];
    const float* W1    = (const float*)d_in[6];
    const float* b1    = (const float*)d_in[7];
    const float* W2    = (const float*)d_in[8];
    const float* b2    = (const float*)d_in[9];
    const float* W3    = (const float*)d_in[10];
    const float* b3    = (const float*)d_in[11];
    const float* W4    = (const float*)d_in[12];
    const float* b4    = (const float*)d_in[13];
    u32* ws = (u32*)d_ws;

    pack_w<<<dim3(440), dim3(256), 0, stream>>>(W0, W1, W2, W3, W4, ws);
    liif_mfma<<<dim3(NPIX / PPB), dim3(NTHR), 0, stream>>>(
        x, coord, cell, lr, b0, b1, b2, b3, b4, ws, (float*)d_out);
}